// Round 2
// 3445.923 us; speedup vs baseline: 1.1130x; 1.1130x over previous
//
#include <hip/hip_runtime.h>
#include <hip/hip_bf16.h>

// ---------------------------------------------------------------------------
// 2-layer tanh RNN (B=128, T=512, H=1024) + LN + vocab projection.
// Persistent fused pipeline, weight-stationary f16 fragments in VGPRs,
// per-group (16 batch rows) spin barriers.
//
//   L0 : h0[t]   = tanh(etab[x[:,t]] + Wh0·h0[t-1])        t in [0,512)
//   XP : xp[t-1] = wi1·h0[t-1] + bi1                        t in [1,512]
//   L1 : h1[t-2] = tanh(xp[t-2] + Wh1·h1[t-3])             t in [2,513]
//   PR : out[t-3] = algebraic-LN(h1[t-3]) @ (g*pw)^T + c    t in [3,514]
//
// R7->R8: HYBRID XCD-LOCAL PATH. R7 (full XCD-local incl. barrier) failed
// opaquely; the unprovable piece was the FAST barrier (plain atomic + sc0
// spin -- if the atomic's coherence point differs from the sc0 read path,
// the group deadlocks). R8 keeps the XCD-local sc0 DATA path (A-tile stage,
// xp loads, h/xp stores -- the bulk of per-step IF latency) but reverts the
// barrier to the R6-proven agent-scope (sc0|sc1, IF) atomic + spin for BOTH
// paths. Producers drain sc0 stores via in-asm s_waitcnt vmcnt(0) (acked at
// the group's XCD L2) BEFORE the IF arrival atomic; consumers observe the
// release at IF then sc0-load from the same L2 -> sound release/acquire.
// A falsely-uniform group can only produce wrong data now, never a hang.
//
// Group->XCD mapping is DETECTED, not assumed: each block reads
// HW_REG_XCC_ID (m09-verified), publishes agent-scope; group uses FAST only
// if all 26 blocks share one XCD, else the R6 agent-scope data path.
//
// LDS note: As row stride 516 dwords gives the uniform-minimum 8 dwords/bank
// for all wave64 b128 patterns; SQ_LDS_BANK_CONFLICT ~1.09e8 is intrinsic.
//
// INPUT DTYPE DETECTED AT RUNTIME (bf16 vs fp32), flag steers all I/O.
// ws need: 3.01 MB.
// ---------------------------------------------------------------------------

typedef __bf16 bf16;
typedef _Float16 f16;
typedef _Float16 f16x8 __attribute__((ext_vector_type(8)));
typedef float f32x4 __attribute__((ext_vector_type(4)));
typedef unsigned long long u64;

#define TSTEPS 512
#define BATCH  128
#define HID    1024
#define NST    515

__device__ __forceinline__ f32x4 mfma16(f16x8 a, f16x8 b, f32x4 c) {
    return __builtin_amdgcn_mfma_f32_16x16x32_f16(a, b, c, 0, 0, 0);
}

// ---- agent-coherent (sc0|sc1, L1/L2-bypassing) helpers (SLOW path) ----
__device__ __forceinline__ f16x8 lda16(const f16* p) {   // 16B via 2x8B
    union { u64 u[2]; f16x8 v; } c;
    c.u[0] = __hip_atomic_load((const u64*)p,     __ATOMIC_RELAXED, __HIP_MEMORY_SCOPE_AGENT);
    c.u[1] = __hip_atomic_load((const u64*)p + 1, __ATOMIC_RELAXED, __HIP_MEMORY_SCOPE_AGENT);
    return c.v;
}
__device__ __forceinline__ void sth2(f16* p, f16 v) {    // 2B coherent store
    union { f16 f; unsigned short s; } c; c.f = v;
    __hip_atomic_store((unsigned short*)p, c.s, __ATOMIC_RELAXED, __HIP_MEMORY_SCOPE_AGENT);
}
__device__ __forceinline__ void stf4(float* p, float v) { // 4B coherent store
    union { float f; unsigned u; } c; c.f = v;
    __hip_atomic_store((unsigned*)p, c.u, __ATOMIC_RELAXED, __HIP_MEMORY_SCOPE_AGENT);
}
__device__ __forceinline__ float ldf4c(const float* p) {  // 4B coherent load
    union { float f; unsigned u; } c;
    c.u = __hip_atomic_load((const unsigned*)p, __ATOMIC_RELAXED, __HIP_MEMORY_SCOPE_AGENT);
    return c.f;
}

__device__ __forceinline__ unsigned f16bits32(f16 v) {
    union { f16 f; unsigned short s; } c; c.f = v; return (unsigned)c.s;
}

// dual-dtype scalar load (read-only inputs, plain cached)
__device__ __forceinline__ float ldf(const void* p, size_t i, bool f32) {
    return f32 ? ((const float*)p)[i] : (float)((const bf16*)p)[i];
}

// --------------------------- dtype detector --------------------------------
__global__ void det_kernel(const unsigned short* __restrict__ e, unsigned* __restrict__ flag) {
    int tid = threadIdx.x;                       // 1 block x 256
    int cnt = 0;
    for (int i = tid; i < 1024; i += 256) {
        unsigned short u = e[i];
        int ex = (u >> 7) & 0xFF;
        if ((ex >= 110 && ex <= 131) || u == 0) cnt++;
    }
    __shared__ int sh[256];
    sh[tid] = cnt; __syncthreads();
    for (int s = 128; s > 0; s >>= 1) { if (tid < s) sh[tid] += sh[tid + s]; __syncthreads(); }
    if (tid == 0) *flag = (sh[0] >= 768) ? 0u : 1u;
}

// --------------------------- setup kernels ---------------------------------
__global__ void etab_kernel(const void* __restrict__ emb, const void* __restrict__ wi0,
                            const void* __restrict__ bi0, const unsigned* __restrict__ flag,
                            float* __restrict__ etab) {
    const bool f32 = (*flag != 0);
    int i = blockIdx.x * 256 + threadIdx.x;      // 1024 blocks
    int v = i >> 10, ch = i & 1023;
    float s = ldf(bi0, ch, f32);
    for (int e = 0; e < 512; ++e)
        s += ldf(emb, (size_t)v * 512 + e, f32) * ldf(wi0, (size_t)ch * 512 + e, f32);
    etab[i] = s;
}

__global__ void c12_kernel(const void* __restrict__ pw, const void* __restrict__ g,
                           const void* __restrict__ be, const void* __restrict__ pb,
                           const unsigned* __restrict__ flag, float* __restrict__ c12) {
    const bool f32 = (*flag != 0);
    int v = threadIdx.x;                         // 1 block x 256
    float a = 0.f, b = 0.f;
    for (int k = 0; k < 1024; ++k) {
        float w = ldf(pw, (size_t)v * 1024 + k, f32);
        a += (float)(f16)(w * ldf(g, k, f32));
        b += w * ldf(be, k, f32);
    }
    c12[v] = a;
    c12[256 + v] = b + ldf(pb, v, f32);
}

// --------------------------- templated step loop ---------------------------
// FAST=true : group-private DATA via sc0-only (XCD-local L2 coherent).
// FAST=false: original agent-scope (sc0|sc1, Infinity Cache) data path.
// Barrier is agent-scope (R6-proven) in BOTH paths.
template<bool FAST>
__device__ __forceinline__ void run_loop(
    const int role, const int gbase,
    const int tid, const int lane, const int n, const int quad,
    const int ch, const int outv,
    const f16x8 (&wf)[32], const float bias, const float c1v, const float c2v,
    const bool f32io,
    const float* __restrict__ etab, const int* __restrict__ x,
    f16* __restrict__ h0buf, f16* __restrict__ h1buf, float* __restrict__ xpf,
    void* __restrict__ out, unsigned* __restrict__ myc,
    f16 (&As)[16][1032])
{
    for (int t = 0; t < NST; ++t) {
        bool active;
        f16* rbuf;
        if (role == 0)      { active = (t < 512);            rbuf = h0buf; }
        else if (role == 1) { active = (t >= 1 && t <= 512); rbuf = h0buf; }
        else if (role == 2) { active = (t >= 2 && t <= 513); rbuf = h1buf; }
        else                { active = (t >= 3 && t <= 514); rbuf = h1buf; }

        if (active) {   // block-uniform
            const f16* Abase = rbuf + ((t + 1) & 1) * (BATCH * HID)
                             + (size_t)gbase * HID;

            // epilogue operands (issued before staging so latency overlaps)
            float ev[4] = {0.f, 0.f, 0.f, 0.f};
            if (role == 0) {
#pragma unroll
                for (int r = 0; r < 4; ++r) {
                    int b = gbase + quad * 4 + r;
                    ev[r] = etab[(size_t)x[b * TSTEPS + t] * HID + ch];
                }
            } else if (role == 2) {
                const float* xs = xpf + (t & 1) * (BATCH * HID);
                if constexpr (FAST) {
                    const float* p0 = xs + (size_t)(gbase + quad * 4 + 0) * HID + ch;
                    const float* p1 = xs + (size_t)(gbase + quad * 4 + 1) * HID + ch;
                    const float* p2 = xs + (size_t)(gbase + quad * 4 + 2) * HID + ch;
                    const float* p3 = xs + (size_t)(gbase + quad * 4 + 3) * HID + ch;
                    asm volatile(
                        "global_load_dword %0, %4, off sc0\n\t"
                        "global_load_dword %1, %5, off sc0\n\t"
                        "global_load_dword %2, %6, off sc0\n\t"
                        "global_load_dword %3, %7, off sc0\n\t"
                        "s_waitcnt vmcnt(0)"
                        : "=&v"(ev[0]), "=&v"(ev[1]), "=&v"(ev[2]), "=&v"(ev[3])
                        : "v"(p0), "v"(p1), "v"(p2), "v"(p3)
                        : "memory");
                } else {
#pragma unroll
                    for (int r = 0; r < 4; ++r)
                        ev[r] = ldf4c(xs + (size_t)(gbase + quad * 4 + r) * HID + ch);
                }
            }

            // ---- cooperative A-tile stage: 32 KB, once per block ----
            if constexpr (FAST) {
                const f16* ga[4]; f16* da[4];
#pragma unroll
                for (int it = 0; it < 4; ++it) {
                    int idx = it * 512 + tid;        // 2048 chunks of 16B
                    int row = idx >> 7, col = (idx & 127) << 3;
                    ga[it] = Abase + (size_t)row * HID + col;
                    da[it] = &As[row][col];
                }
                f32x4 v0, v1, v2, v3;
                asm volatile(
                    "global_load_dwordx4 %0, %4, off sc0\n\t"
                    "global_load_dwordx4 %1, %5, off sc0\n\t"
                    "global_load_dwordx4 %2, %6, off sc0\n\t"
                    "global_load_dwordx4 %3, %7, off sc0\n\t"
                    "s_waitcnt vmcnt(0)"
                    : "=&v"(v0), "=&v"(v1), "=&v"(v2), "=&v"(v3)
                    : "v"(ga[0]), "v"(ga[1]), "v"(ga[2]), "v"(ga[3])
                    : "memory");
                *(f32x4*)da[0] = v0;
                *(f32x4*)da[1] = v1;
                *(f32x4*)da[2] = v2;
                *(f32x4*)da[3] = v3;
            } else {
#pragma unroll
                for (int it = 0; it < 4; ++it) {
                    int idx = it * 512 + tid;
                    int row = idx >> 7, col = (idx & 127) << 3;
                    f16x8 v = lda16(Abase + (size_t)row * HID + col);
                    *(f16x8*)&As[row][col] = v;
                }
            }

            __syncthreads();    // A-tile visible to all waves

            float mu = 0.f, rs = 0.f;
            if (role == 3) {    // LN stats from the LDS copy
                const f16* srow = &As[n][quad * 256];
                float sum = 0.f, sq = 0.f;
#pragma unroll
                for (int i = 0; i < 256; i += 8) {
                    f16x8 hv = *(const f16x8*)(srow + i);
#pragma unroll
                    for (int j = 0; j < 8; ++j) {
                        float e = (float)hv[j];
                        sum += e; sq += e * e;
                    }
                }
                sum += __shfl_xor(sum, 16); sq += __shfl_xor(sq, 16);
                sum += __shfl_xor(sum, 32); sq += __shfl_xor(sq, 32);
                mu = sum * (1.f / 1024.f);
                float var = sq * (1.f / 1024.f) - mu * mu;
                rs = rsqrtf(fmaxf(var, 0.f) + 1e-5f);
            }

            const f16* arow = &As[n][quad * 8];
            f32x4 a0 = {0,0,0,0}, a1 = {0,0,0,0}, a2 = {0,0,0,0}, a3 = {0,0,0,0};
#pragma unroll
            for (int kt = 0; kt < 32; kt += 4) {
                a0 = mfma16(*(const f16x8*)(arow + (kt + 0) * 32), wf[kt + 0], a0);
                a1 = mfma16(*(const f16x8*)(arow + (kt + 1) * 32), wf[kt + 1], a1);
                a2 = mfma16(*(const f16x8*)(arow + (kt + 2) * 32), wf[kt + 2], a2);
                a3 = mfma16(*(const f16x8*)(arow + (kt + 3) * 32), wf[kt + 3], a3);
            }
            f32x4 acc = (a0 + a1) + (a2 + a3);

            if (role == 0 || role == 2) {
                f16* dw = ((role == 0) ? h0buf : h1buf) + (t & 1) * (BATCH * HID);
                if constexpr (FAST) {
                    unsigned u0 = f16bits32((f16)tanhf(acc[0] + ev[0]));
                    unsigned u1 = f16bits32((f16)tanhf(acc[1] + ev[1]));
                    unsigned u2 = f16bits32((f16)tanhf(acc[2] + ev[2]));
                    unsigned u3 = f16bits32((f16)tanhf(acc[3] + ev[3]));
                    f16* q0 = dw + (size_t)(gbase + quad * 4 + 0) * HID + ch;
                    f16* q1 = dw + (size_t)(gbase + quad * 4 + 1) * HID + ch;
                    f16* q2 = dw + (size_t)(gbase + quad * 4 + 2) * HID + ch;
                    f16* q3 = dw + (size_t)(gbase + quad * 4 + 3) * HID + ch;
                    // in-asm vmcnt(0): stores acked at XCD L2 BEFORE this wave
                    // reaches the barrier / the IF-scope arrival atomic.
                    asm volatile(
                        "global_store_short %4, %0, off sc0\n\t"
                        "global_store_short %5, %1, off sc0\n\t"
                        "global_store_short %6, %2, off sc0\n\t"
                        "global_store_short %7, %3, off sc0\n\t"
                        "s_waitcnt vmcnt(0)"
                        :: "v"(u0), "v"(u1), "v"(u2), "v"(u3),
                           "v"(q0), "v"(q1), "v"(q2), "v"(q3)
                        : "memory");
                } else {
#pragma unroll
                    for (int r = 0; r < 4; ++r) {
                        int b = gbase + quad * 4 + r;
                        sth2(dw + (size_t)b * HID + ch, (f16)tanhf(acc[r] + ev[r]));
                    }
                }
            } else if (role == 1) {
                float* dw = xpf + ((t + 1) & 1) * (BATCH * HID);
                if constexpr (FAST) {
                    float w0 = acc[0] + bias, w1 = acc[1] + bias;
                    float w2 = acc[2] + bias, w3 = acc[3] + bias;
                    float* q0 = dw + (size_t)(gbase + quad * 4 + 0) * HID + ch;
                    float* q1 = dw + (size_t)(gbase + quad * 4 + 1) * HID + ch;
                    float* q2 = dw + (size_t)(gbase + quad * 4 + 2) * HID + ch;
                    float* q3 = dw + (size_t)(gbase + quad * 4 + 3) * HID + ch;
                    asm volatile(
                        "global_store_dword %4, %0, off sc0\n\t"
                        "global_store_dword %5, %1, off sc0\n\t"
                        "global_store_dword %6, %2, off sc0\n\t"
                        "global_store_dword %7, %3, off sc0\n\t"
                        "s_waitcnt vmcnt(0)"
                        :: "v"(w0), "v"(w1), "v"(w2), "v"(w3),
                           "v"(q0), "v"(q1), "v"(q2), "v"(q3)
                        : "memory");
                } else {
#pragma unroll
                    for (int r = 0; r < 4; ++r) {
                        int b = gbase + quad * 4 + r;
                        stf4(dw + (size_t)b * HID + ch, acc[r] + bias);
                    }
                }
            } else {
                int s = t - 3;
#pragma unroll
                for (int r = 0; r < 4; ++r) {
                    int m = quad * 4 + r;
                    float mm = __shfl(mu, m), rr = __shfl(rs, m);
                    float lv = rr * acc[r] - rr * mm * c1v + c2v;
                    size_t oi = ((size_t)(gbase + m) * TSTEPS + s) * 256 + outv;
                    if (f32io) ((float*)out)[oi] = lv;
                    else       ((bf16*)out)[oi]  = (bf16)lv;
                }
            }
        }

        // ---- per-group barrier (26 blocks), agent-scope (R6-proven) ----
        __syncthreads();    // all waves' stores drained (asm did vmcnt(0))
        if (tid == 0) {
            __hip_atomic_fetch_add(myc, 1u, __ATOMIC_RELAXED, __HIP_MEMORY_SCOPE_AGENT);
            const unsigned tgt = 26u * (unsigned)(t + 1);
            while (__hip_atomic_load(myc, __ATOMIC_RELAXED, __HIP_MEMORY_SCOPE_AGENT) < tgt)
                __builtin_amdgcn_s_sleep(1);
        }
        __syncthreads();
    }
}

// --------------------------- persistent mega kernel ------------------------
// grid 208 = 8 groups x 26 blocks; 512 thr (8 waves).
// rid = bid>>3: 0-7 L0, 8-15 XP, 16-23 L1, 24-25 PR.
__global__ __launch_bounds__(512, 2) void mega_kernel(
    const void* __restrict__ wh0, const void* __restrict__ wi1,
    const void* __restrict__ wh1, const void* __restrict__ pw,
    const void* __restrict__ lng, const void* __restrict__ bi1,
    const float* __restrict__ etab, const float* __restrict__ c12,
    const int* __restrict__ x, const unsigned* __restrict__ flag,
    f16* __restrict__ h0buf, f16* __restrict__ h1buf, float* __restrict__ xpf,
    void* __restrict__ out, unsigned* __restrict__ cnt)
{
    const bool f32io = (*flag != 0);
    const int bid  = blockIdx.x;
    const int g    = bid & 7, rid = bid >> 3;
    const int role = rid >> 3;                   // 0 L0, 1 XP, 2 L1, 3 PR
    const int slice = rid & 7;
    const int tid  = threadIdx.x;
    const int wave = tid >> 6, lane = tid & 63;
    const int n    = lane & 15, quad = lane >> 4;
    const int gbase = g * 16;
    unsigned* const myc = cnt + g * 32;

    // A-tile staging buffer: 16 rows x 1032 (stride 516 dwords -> uniform
    // 8 dwords/bank for all b128 patterns, the wave64 minimum). 33 KB LDS.
    __shared__ __align__(16) f16 As[16][1032];

    // stationary f16 weight fragments: 32 x f16x8 = 128 VGPR
    f16x8 wf[32];
    float bias = 0.f, c1v = 0.f, c2v = 0.f;
    int ch = 0, outv = 0;
    if (role < 3) {
        ch = slice * 128 + wave * 16 + n;
        const void* W = (role == 0) ? wh0 : ((role == 1) ? wi1 : wh1);
#pragma unroll
        for (int kt = 0; kt < 32; ++kt) {
            f16x8 t;
#pragma unroll
            for (int j = 0; j < 8; ++j)
                t[j] = (f16)ldf(W, (size_t)ch * HID + kt * 32 + quad * 8 + j, f32io);
            wf[kt] = t;
        }
        if (role == 1) bias = ldf(bi1, ch, f32io);
    } else {
        int tile = slice * 8 + wave;             // 0..15
        outv = tile * 16 + n;
#pragma unroll
        for (int kt = 0; kt < 32; ++kt) {
            f16x8 t;
#pragma unroll
            for (int j = 0; j < 8; ++j) {
                int k = kt * 32 + quad * 8 + j;
                t[j] = (f16)(ldf(pw, (size_t)outv * HID + k, f32io) * ldf(lng, k, f32io));
            }
            wf[kt] = t;
        }
        c1v = c12[outv];
        c2v = c12[256 + outv];
    }

    // ---- XCD-uniformity detection (agent-scope; once) ----
    // Slots cnt[256+bid] hold 0x100|xcc after publish; memset zeroed them.
    // Publish-then-wait over co-resident blocks (same premise as the main
    // barrier, proven over 515 steps in R6) -> cannot deadlock if R6 didn't.
    unsigned xcc = 0;
    asm volatile("s_getreg_b32 %0, hwreg(HW_REG_XCC_ID)" : "=s"(xcc));
    xcc &= 0xFu;
    __shared__ int fsh;
    if (tid == 0) {
        const unsigned my = 0x100u | xcc;
        __hip_atomic_store(cnt + 256 + bid, my, __ATOMIC_RELAXED, __HIP_MEMORY_SCOPE_AGENT);
        int ok = 1;
        for (int r = 0; r < 26; ++r) {
            unsigned v;
            for (;;) {
                v = __hip_atomic_load(cnt + 256 + g + 8 * r, __ATOMIC_RELAXED, __HIP_MEMORY_SCOPE_AGENT);
                if (v & 0x100u) break;
                __builtin_amdgcn_s_sleep(2);
            }
            if (v != my) ok = 0;
        }
        fsh = ok;
    }
    __syncthreads();
    const bool fast = (fsh != 0);

    if (fast)
        run_loop<true >(role, gbase, tid, lane, n, quad, ch, outv, wf, bias, c1v, c2v,
                        f32io, etab, x, h0buf, h1buf, xpf, out, myc, As);
    else
        run_loop<false>(role, gbase, tid, lane, n, quad, ch, outv, wf, bias, c1v, c2v,
                        f32io, etab, x, h0buf, h1buf, xpf, out, myc, As);
}

// --------------------------- launch -----------------------------------------
extern "C" void kernel_launch(void* const* d_in, const int* in_sizes, int n_in,
                              void* d_out, int out_size, void* d_ws, size_t ws_size,
                              hipStream_t stream) {
    const void* emb    = d_in[0];
    const void* wi0    = d_in[1];
    const void* bi0    = d_in[2];
    const void* wh0    = d_in[3];
    const void* wi1    = d_in[4];
    const void* bi1    = d_in[5];
    const void* wh1    = d_in[6];
    const void* ln_g   = d_in[7];
    const void* ln_b   = d_in[8];
    const void* proj_w = d_in[9];
    const void* proj_b = d_in[10];
    const int*  x      = (const int*)d_in[11];
    char* ws = (char*)d_ws;

    // ws map (bytes), total 3,151,936
    float*    etab  = (float*)(ws + 0);             // 1,048,576
    float*    c12   = (float*)(ws + 1048576);       // 2,048
    unsigned* flag  = (unsigned*)(ws + 1050624);    // 64
    f16*      h0buf = (f16*)(ws + 1050688);         // 524,288 ping-pong
    f16*      h1buf = (f16*)(ws + 1574976);         // 524,288 ping-pong
    float*    xpf   = (float*)(ws + 2099264);       // 1,048,576 ping-pong
    unsigned* cnt   = (unsigned*)(ws + 3147840);    // 4,096 (barriers + xcd slots)
    if (ws_size < 3151936u) return;  // bail signature: out stays 0

    // zero flag + h/xp ping-pongs + counters/slots: [1050624, 3151936)
    hipMemsetAsync(ws + 1050624, 0, 3151936 - 1050624, stream);

    det_kernel<<<1, 256, 0, stream>>>((const unsigned short*)emb, flag);
    etab_kernel<<<1024, 256, 0, stream>>>(emb, wi0, bi0, flag, etab);
    c12_kernel<<<1, 256, 0, stream>>>(proj_w, ln_g, ln_b, proj_b, flag, c12);
    mega_kernel<<<208, 512, 0, stream>>>(wh0, wi1, wh1, proj_w, ln_g, bi1,
                                         etab, c12, x, flag,
                                         h0buf, h1buf, xpf, d_out, cnt);
}